// Round 14
// baseline (814.530 us; speedup 1.0000x reference)
//
#include <hip/hip_runtime.h>
#include <hip/hip_bf16.h>

typedef __bf16 bf16_t;
typedef __bf16 bf16x4 __attribute__((ext_vector_type(4)));
typedef __bf16 bf16x8 __attribute__((ext_vector_type(8)));
typedef float f32x4 __attribute__((ext_vector_type(4)));

union FragU { bf16x8 v; bf16x4 h[2]; };
union F4U { float4 v; float f[4]; };

constexpr int BB = 32, SS = 512, DD = 512, FFD = 2048, LL = 4, HH = 8;

// Fragment-order permutation of k within each 32-elem chunk: granule order
// [0,4,1,5,2,6,3,7] -> MFMA fragment g is one contiguous 16B block.
__device__ __forceinline__ int permk(int k) {
  int g = (k >> 2) & 7;
  int pos = (g < 4) ? (g << 1) : (((g - 4) << 1) | 1);
  return (k & ~31) | (pos << 2) | (k & 3);
}
__device__ __forceinline__ int permpos(int c) {  // position of k (c=k&31) within chunk
  int gq = c >> 2;
  int pos = (gq < 4) ? (gq << 1) : (((gq - 4) << 1) | 1);
  return pos * 4 + (c & 3);
}

__device__ __forceinline__ void gload_lds16(const bf16_t* g, bf16_t* l) {
  __builtin_amdgcn_global_load_lds(
      (const __attribute__((address_space(1))) void*)g,
      (__attribute__((address_space(3))) void*)l, 16, 0, 0);
}

template<int N> __device__ __forceinline__ void vmwait() {
  asm volatile("s_waitcnt vmcnt(%0)" :: "n"(N) : "memory");
}
__device__ __forceinline__ void lgkmwait0() {
  asm volatile("s_waitcnt lgkmcnt(0)" ::: "memory");
}
__device__ __forceinline__ void barrier_raw() {
  asm volatile("s_barrier" ::: "memory");
}

#define MFMA_ACC(d, a, b) d = __builtin_amdgcn_mfma_f32_16x16x32_bf16((a).v, (b).v, d, 0, 0, 0)

// ---------------- positional-embedding table [S][D] ----------------
__global__ void pe_kernel(float* __restrict__ pe) {
  int idx = blockIdx.x * blockDim.x + threadIdx.x;  // pair index
  if (idx >= SS * DD / 2) return;
  int p = idx % (DD / 2);
  int s = idx / (DD / 2);
  float div = expf((float)(2 * p) * (-9.210340371976184f / (float)DD));
  float a = (float)s * div;
  pe[s * DD + 2 * p]     = sinf(a);
  pe[s * DD + 2 * p + 1] = cosf(a);
}

// ---------------- permute gamma/beta into permk order (per layer) ----------------
__global__ void gbperm_kernel(const float* __restrict__ g1, const float* __restrict__ b1,
                              const float* __restrict__ g2, const float* __restrict__ b2,
                              float* __restrict__ g1p, float* __restrict__ b1p,
                              float* __restrict__ g2p, float* __restrict__ b2p) {
  int idx = blockIdx.x * 256 + threadIdx.x;
  if (idx >= LL * DD) return;
  int p = (idx & ~511) | permk(idx & 511);
  g1p[p] = g1[idx]; b1p[p] = b1[idx]; g2p[p] = g2[idx]; b2p[p] = b2[idx];
}

// ---------------- transpose-cast: src [K][N] f32 -> dst [N][K]_perm bf16 ----
__global__ __launch_bounds__(256) void tcast_kernel(const float* __restrict__ src,
                                                    bf16_t* __restrict__ dst,
                                                    int K, int N) {
  __shared__ float tile[32][33];
  size_t mat = (size_t)blockIdx.z * (size_t)K * (size_t)N;
  int k0 = blockIdx.y * 32, n0 = blockIdx.x * 32;
  int t = threadIdx.x;
  int r = t >> 3, c4 = (t & 7) * 4;
  const float4 v = *reinterpret_cast<const float4*>(&src[mat + (size_t)(k0 + r) * N + n0 + c4]);
  tile[r][c4 + 0] = v.x; tile[r][c4 + 1] = v.y; tile[r][c4 + 2] = v.z; tile[r][c4 + 3] = v.w;
  __syncthreads();
  bf16x4 o;
  o[0] = (bf16_t)tile[c4 + 0][r];
  o[1] = (bf16_t)tile[c4 + 1][r];
  o[2] = (bf16_t)tile[c4 + 2][r];
  o[3] = (bf16_t)tile[c4 + 3][r];
  *reinterpret_cast<bf16x4*>(&dst[mat + permk((n0 + r) * K + k0 + c4)]) = o;
}

// ---------------- xb = bf16_perm(q + pe), yb = bf16_perm(qa + pe) ----------------
__global__ void addpe_kernel(const float* __restrict__ q, const float* __restrict__ qa,
                             const float* __restrict__ pe,
                             bf16_t* __restrict__ xb, bf16_t* __restrict__ yb) {
  int i = blockIdx.x * blockDim.x + threadIdx.x;  // float4 index
  int pei = i & (SS * DD / 4 - 1);
  float4 pv = reinterpret_cast<const float4*>(pe)[pei];
  float4 qv = reinterpret_cast<const float4*>(q)[i];
  float4 av = reinterpret_cast<const float4*>(qa)[i];
  bf16x4 xo, yo;
  xo[0] = (bf16_t)(qv.x + pv.x); xo[1] = (bf16_t)(qv.y + pv.y);
  xo[2] = (bf16_t)(qv.z + pv.z); xo[3] = (bf16_t)(qv.w + pv.w);
  yo[0] = (bf16_t)(av.x + pv.x); yo[1] = (bf16_t)(av.y + pv.y);
  yo[2] = (bf16_t)(av.z + pv.z); yo[3] = (bf16_t)(av.w + pv.w);
  int kp = permk(4 * i);
  *reinterpret_cast<bf16x4*>(&xb[kp]) = xo;
  *reinterpret_cast<bf16x4*>(&yb[kp]) = yo;
}

// ---------------- 2-phase GEMM: C[M,N] = A[M,K]_perm @ Bt[N,K]_perm^T + bias ----
// Counted-vmcnt double buffer (round-7 proven). OMODE: 1 = bf16 permk row-major,
// 2 = V^T attn layout (vtg). ATILED: A is in 256x256-tiled layout
// [m>>8][k>>8][m&255][perm(k&255)] (used for h1 in FF2).
template<int OMODE, bool RELU, bool ATILED = false>
__global__ __launch_bounds__(256, 2) void gemm_kernel(const bf16_t* __restrict__ A,
                                                      const bf16_t* __restrict__ Bt,
                                                      const float* __restrict__ bias,
                                                      void* __restrict__ Cout,
                                                      int N, int K, int nnt) {
  __shared__ bf16_t a_s[2][128 * 64];
  __shared__ bf16_t b_s[2][128 * 64];
  const int t = threadIdx.x;
  const int nwg = gridDim.x;
  const int bid = blockIdx.x;
  const int wg = (bid & 7) * (nwg >> 3) + (bid >> 3);   // bijective XCD swizzle
  const int m0 = (wg / nnt) * 128, n0 = (wg % nnt) * 128;
  const int l = t & 63, w = t >> 6, g = l >> 4, ln = l & 15;
  const int wm = (w >> 1) * 64, wn = (w & 1) * 64;
  const int tr = t >> 3;
  const int bsrc = ((t & 7) ^ (tr & 7)) * 8;
  const bf16_t* Asrc;
  size_t arstr;
  if constexpr (ATILED) {
    Asrc = A + (size_t)(m0 >> 8) * ((size_t)K * 256) + (size_t)((m0 & 255) + tr) * 256 + bsrc;
    arstr = 8192;   // 32 rows * 256
  } else {
    Asrc = A + (size_t)(m0 + tr) * K + bsrc;
    arstr = (size_t)32 * K;
  }
  const bf16_t* Bsrc = Bt + (size_t)(n0 + tr) * K + bsrc;
  const size_t rstr = (size_t)32 * K;
  const int x0 = (g ^ (ln & 7)) * 8;
  const int x1 = ((4 + g) ^ (ln & 7)) * 8;

  auto STAGE = [&](int p, int T) {
    const int ka = ATILED ? ((T >> 2) * 65536 + (T & 3) * 64) : (T << 6);
    const int kb = T << 6;
#pragma unroll
    for (int i = 0; i < 4; i++) gload_lds16(Asrc + ka + i * arstr, &a_s[p][(i * 256 + t) * 8]);
#pragma unroll
    for (int i = 0; i < 4; i++) gload_lds16(Bsrc + kb + i * rstr, &b_s[p][(i * 256 + t) * 8]);
  };

  f32x4 acc[4][4] = {};
  const int NT = K >> 6;
  STAGE(0, 0);
  STAGE(1, 1);
  for (int T = 0; T < NT; T++) {
    const int p = T & 1;
    if (T + 1 < NT) vmwait<8>(); else vmwait<0>();   // own tile-T loads landed
    barrier_raw();                                   // all waves' tile-T loads landed
    __builtin_amdgcn_sched_barrier(0);
#pragma unroll
    for (int kc = 0; kc < 2; kc++) {
      const int xo = kc ? x1 : x0;
      FragU fa[4], fb[4];
#pragma unroll
      for (int mi = 0; mi < 4; mi++)
        fa[mi].v = *reinterpret_cast<const bf16x8*>(&a_s[p][(wm + mi * 16 + ln) * 64 + xo]);
#pragma unroll
      for (int ni = 0; ni < 4; ni++)
        fb[ni].v = *reinterpret_cast<const bf16x8*>(&b_s[p][(wn + ni * 16 + ln) * 64 + xo]);
      __builtin_amdgcn_s_setprio(1);
#pragma unroll
      for (int mi = 0; mi < 4; mi++)
#pragma unroll
        for (int ni = 0; ni < 4; ni++)
          MFMA_ACC(acc[mi][ni], fa[mi], fb[ni]);
      __builtin_amdgcn_s_setprio(0);
    }
    __builtin_amdgcn_sched_barrier(0);
    barrier_raw();                                   // all waves done reading buffer p
    if (T + 2 < NT) STAGE(p, T + 2);                 // refill p; stays in flight
  }

  if constexpr (OMODE == 2) {
    const int brow = m0 >> 9;
    const int s0b = (m0 & 511) + wm;
    bf16_t* vout = reinterpret_cast<bf16_t*>(Cout);
#pragma unroll
    for (int ni = 0; ni < 4; ni++) {
      const int d = n0 + wn + ni * 16 + ln;
      const float bv = bias[d];
      const int h = d >> 6, dd = d & 63;
      bf16_t* vrow = vout + ((size_t)((brow * HH + h) * 64 + dd)) * SS;
#pragma unroll
      for (int mi = 0; mi < 4; mi++) {
        const int s0 = s0b + mi * 16 + g * 4;
        const int jt = s0 >> 6, jj = s0 & 63;
        const int js = jj >> 5, half = (jj >> 4) & 1;
        const int blkx = (js * 4 + g) ^ (dd & 7);
        bf16x4 o;
#pragma unroll
        for (int r = 0; r < 4; r++) o[r] = (bf16_t)(acc[mi][ni][r] + bv);
        *reinterpret_cast<bf16x4*>(&vrow[jt * 64 + blkx * 8 + half * 4]) = o;
      }
    }
  } else {
#pragma unroll
    for (int ni = 0; ni < 4; ni++) {
      const int col = n0 + wn + ni * 16 + ln;
      const float bv = bias[col];
      const int colp = permk(col);
#pragma unroll
      for (int mi = 0; mi < 4; mi++)
#pragma unroll
        for (int r = 0; r < 4; r++) {
          int row = m0 + wm + mi * 16 + g * 4 + r;
          float o = acc[mi][ni][r] + bv;
          if (RELU) o = fmaxf(o, 0.f);
          reinterpret_cast<bf16_t*>(Cout)[(size_t)row * N + colp] = (bf16_t)o;
        }
    }
  }
}

// ---------------- gemmW (FF1): R9's exact proven kernel; output h1 TILED ----------
// BM=BN=256, 8 waves (2Mx4N, wave=128x64); 4 phases, raw barriers, counted vmcnt(8),
// stage-into-freed-rows. Scatter epilogue writes the block's own contiguous 128KB
// tile h1[m>>8][f>>8][m&255][perm(f&255)] -> no partial-line L2 evictions.
__global__ __launch_bounds__(512, 1) void gemmW_kernel(const bf16_t* __restrict__ A,
                                                       const bf16_t* __restrict__ Bt,
                                                       const float* __restrict__ bias,
                                                       bf16_t* __restrict__ Cout,
                                                       int N, int K, int nnt) {
  __shared__ bf16_t a_s[2][256 * 64];   // 64 KB
  __shared__ bf16_t b_s[2][256 * 64];   // 64 KB
  const int t = threadIdx.x;
  const int bid = blockIdx.x, nwg = gridDim.x;
  const int wg = (bid & 7) * (nwg >> 3) + (bid >> 3);
  const int m0 = (wg / nnt) * 256, n0 = (wg % nnt) * 256;
  const int l = t & 63, w = t >> 6, g = l >> 4, ln = l & 15, lnx = l & 7;
  const int wr = w >> 2, wc = w & 3;    // 2M x 4N wave grid; per-wave 128x64
  const int tr = t >> 3;
  const int bsrc = ((t & 7) ^ (tr & 7)) * 8;
  const bf16_t* Asrc = A + (size_t)(m0 + tr) * K + bsrc;
  const bf16_t* Bsrc = Bt + (size_t)(n0 + tr) * K + bsrc;
  const size_t rstr = (size_t)64 * K;
  const int x0 = (g ^ lnx) * 8;
  const int x1 = ((4 + g) ^ lnx) * 8;

  auto STA = [&](int q, int T2, int i) {
    gload_lds16(Asrc + (T2 << 6) + i * rstr, &a_s[q][(i * 512 + t) * 8]);
  };
  auto STB = [&](int q, int T2, int i) {
    gload_lds16(Bsrc + (T2 << 6) + i * rstr, &b_s[q][(i * 512 + t) * 8]);
  };

  f32x4 acc[8][4] = {};
  const int NT = K >> 6;
#pragma unroll
  for (int i = 0; i < 4; i++) { STA(0, 0, i); STB(0, 0, i); }
#pragma unroll
  for (int i = 0; i < 4; i++) { STA(1, 1, i); STB(1, 1, i); }
  vmwait<8>();
  barrier_raw();

  for (int T = 0; T < NT; T++) {
    const int p = T & 1;
    const bool st = (T + 2) < NT;
    FragU fa[4], fb[4];
    // ---- P0: A mh0 kc0 + B kc0 -> MFMA(mh0, kc0) ----
#pragma unroll
    for (int mf = 0; mf < 4; mf++)
      fa[mf].v = *reinterpret_cast<const bf16x8*>(&a_s[p][(wr * 128 + mf * 16 + ln) * 64 + x0]);
#pragma unroll
    for (int nf = 0; nf < 4; nf++)
      fb[nf].v = *reinterpret_cast<const bf16x8*>(&b_s[p][(wc * 64 + nf * 16 + ln) * 64 + x0]);
    barrier_raw();
    lgkmwait0();
    __builtin_amdgcn_sched_barrier(0);
    __builtin_amdgcn_s_setprio(1);
#pragma unroll
    for (int mf = 0; mf < 4; mf++)
#pragma unroll
      for (int nf = 0; nf < 4; nf++) MFMA_ACC(acc[mf][nf], fa[mf], fb[nf]);
    __builtin_amdgcn_s_setprio(0);
    barrier_raw();
    // ---- P1: A mh1 kc0 -> MFMA(mh1, kc0) ----
#pragma unroll
    for (int mf = 0; mf < 4; mf++)
      fa[mf].v = *reinterpret_cast<const bf16x8*>(&a_s[p][(wr * 128 + 64 + mf * 16 + ln) * 64 + x0]);
    barrier_raw();
    lgkmwait0();
    __builtin_amdgcn_sched_barrier(0);
    __builtin_amdgcn_s_setprio(1);
#pragma unroll
    for (int mf = 0; mf < 4; mf++)
#pragma unroll
      for (int nf = 0; nf < 4; nf++) MFMA_ACC(acc[4 + mf][nf], fa[mf], fb[nf]);
    __builtin_amdgcn_s_setprio(0);
    barrier_raw();
    // ---- P2: A mh0 kc1 + B kc1; stage A-rounds{0,2}+B (rows done being read) ----
#pragma unroll
    for (int mf = 0; mf < 4; mf++)
      fa[mf].v = *reinterpret_cast<const bf16x8*>(&a_s[p][(wr * 128 + mf * 16 + ln) * 64 + x1]);
#pragma unroll
    for (int nf = 0; nf < 4; nf++)
      fb[nf].v = *reinterpret_cast<const bf16x8*>(&b_s[p][(wc * 64 + nf * 16 + ln) * 64 + x1]);
    barrier_raw();
    if (st) { STA(p, T + 2, 0); STA(p, T + 2, 2); STB(p, T + 2, 0); STB(p, T + 2, 1); STB(p, T + 2, 2); STB(p, T + 2, 3); }
    lgkmwait0();
    __builtin_amdgcn_sched_barrier(0);
    __builtin_amdgcn_s_setprio(1);
#pragma unroll
    for (int mf = 0; mf < 4; mf++)
#pragma unroll
      for (int nf = 0; nf < 4; nf++) MFMA_ACC(acc[mf][nf], fa[mf], fb[nf]);
    __builtin_amdgcn_s_setprio(0);
    barrier_raw();
    // ---- P3: A mh1 kc1; stage A-rounds{1,3}; counted vmwait ----
#pragma unroll
    for (int mf = 0; mf < 4; mf++)
      fa[mf].v = *reinterpret_cast<const bf16x8*>(&a_s[p][(wr * 128 + 64 + mf * 16 + ln) * 64 + x1]);
    barrier_raw();
    if (st) { STA(p, T + 2, 1); STA(p, T + 2, 3); }
    lgkmwait0();
    __builtin_amdgcn_sched_barrier(0);
    __builtin_amdgcn_s_setprio(1);
#pragma unroll
    for (int mf = 0; mf < 4; mf++)
#pragma unroll
      for (int nf = 0; nf < 4; nf++) MFMA_ACC(acc[4 + mf][nf], fa[mf], fb[nf]);
    __builtin_amdgcn_s_setprio(0);
    if (T + 1 < NT) { if (st) vmwait<8>(); else vmwait<0>(); }
    barrier_raw();
  }

  // ---- scatter epilogue into the block's own 128KB tile (dense in L2) ----
  const size_t tbase = (size_t)(m0 >> 8) * ((size_t)N * 256) + (size_t)(n0 >> 8) * 65536;
#pragma unroll
  for (int nf = 0; nf < 4; nf++) {
    const int col_l = wc * 64 + nf * 16 + ln;
    const float bv = bias[n0 + col_l];
    const int colp = (col_l & ~31) | permpos(col_l & 31);
#pragma unroll
    for (int mf = 0; mf < 8; mf++) {
      const int mloc = wr * 128 + mf * 16 + g * 4;
#pragma unroll
      for (int r = 0; r < 4; r++) {
        float o = fmaxf(acc[mf][nf][r] + bv, 0.f);
        Cout[tbase + (size_t)(mloc + r) * 256 + colp] = (bf16_t)o;
      }
    }
  }
}

// ---------------- residual + LayerNorm fully in permk-bf16 space ----------------
template<bool FINAL>
__global__ __launch_bounds__(256) void lnp_kernel(const bf16_t* __restrict__ xb,
                                                  const bf16_t* __restrict__ tb,
                                                  const float* __restrict__ gp,
                                                  const float* __restrict__ bp,
                                                  bf16_t* __restrict__ xbo,
                                                  float* __restrict__ fout) {
  int row = blockIdx.x * 4 + (threadIdx.x >> 6);
  int l = threadIdx.x & 63;
  size_t base = (size_t)row * DD + l * 8;
  FragU xv, tv;
  xv.v = *reinterpret_cast<const bf16x8*>(&xb[base]);
  tv.v = *reinterpret_cast<const bf16x8*>(&tb[base]);
  float vals[8];
  float s = 0.f;
#pragma unroll
  for (int j = 0; j < 8; j++) { vals[j] = (float)xv.v[j] + (float)tv.v[j]; s += vals[j]; }
#pragma unroll
  for (int off = 1; off < 64; off <<= 1) s += __shfl_xor(s, off, 64);
  float mean = s * (1.f / DD);
  float sq = 0.f;
#pragma unroll
  for (int j = 0; j < 8; j++) { float d = vals[j] - mean; sq += d * d; }
#pragma unroll
  for (int off = 1; off < 64; off <<= 1) sq += __shfl_xor(sq, off, 64);
  float rstd = rsqrtf(sq * (1.f / DD) + 1e-5f);
  F4U g0, g1q, b0, b1q;
  g0.v  = *reinterpret_cast<const float4*>(&gp[l * 8]);
  g1q.v = *reinterpret_cast<const float4*>(&gp[l * 8 + 4]);
  b0.v  = *reinterpret_cast<const float4*>(&bp[l * 8]);
  b1q.v = *reinterpret_cast<const float4*>(&bp[l * 8 + 4]);
  float ov[8];
#pragma unroll
  for (int j = 0; j < 4; j++) ov[j]     = (vals[j] - mean) * rstd * g0.f[j] + b0.f[j];
#pragma unroll
  for (int j = 0; j < 4; j++) ov[4 + j] = (vals[4 + j] - mean) * rstd * g1q.f[j] + b1q.f[j];
  if (FINAL) {
    int c = l >> 2, i = l & 3;
    F4U o0, o1;
#pragma unroll
    for (int j = 0; j < 4; j++) { o0.f[j] = ov[j]; o1.f[j] = ov[4 + j]; }
    float* fr = fout + (size_t)row * DD + c * 32 + 4 * i;
    *reinterpret_cast<float4*>(fr) = o0.v;
    *reinterpret_cast<float4*>(fr + 16) = o1.v;
  } else {
    FragU ob;
#pragma unroll
    for (int j = 0; j < 8; j++) ob.v[j] = (bf16_t)ov[j];
    *reinterpret_cast<bf16x8*>(&xbo[base]) = ob.v;
  }
}

// ---------------- fused causal attention, swapped-QK^T, dbuf K/V, counted vmcnt ----
__global__ __launch_bounds__(256) void attn_kernel(const bf16_t* __restrict__ qk,
                                                   const bf16_t* __restrict__ vtg,
                                                   bf16_t* __restrict__ outp,
                                                   const float* __restrict__ bfp) {
  __shared__ bf16_t k_s[2][64 * 64];   // K tiles, block-XOR pre-swizzled via source
  __shared__ bf16_t v_t[2][64 * 64];   // V^T tiles, swizzle baked in global layout
  const int bx = blockIdx.x, h = blockIdx.y, b = blockIdx.z;
  const int t = threadIdx.x, l = t & 63, w = t >> 6, g = l >> 4, ln = l & 15;
  const float sc = 0.125f * (1.f + bfp[0]);
  const size_t base = ((size_t)b * SS) * DD + h * 64;
  const bf16_t* vbase = vtg + ((size_t)((b * HH + h) * 64)) * SS;
  const int NQT = SS / 64;

  auto STAGEKV = [&](int q, int j0) {
    int c1 = t + 256;
    int jr0 = t >> 3, bb0 = t & 7;
    int jr1 = c1 >> 3, bb1 = c1 & 7;
    gload_lds16(qk + base + (size_t)(j0 + jr0) * DD + ((bb0 ^ (jr0 & 7)) * 8), &k_s[q][t * 8]);
    gload_lds16(qk + base + (size_t)(j0 + jr1) * DD + ((bb1 ^ (jr1 & 7)) * 8), &k_s[q][c1 * 8]);
    gload_lds16(vbase + (size_t)jr0 * SS + j0 + bb0 * 8, &v_t[q][t * 8]);
    gload_lds16(vbase + (size_t)jr1 * SS + j0 + bb1 * 8, &v_t[q][c1 * 8]);
  };

  for (int pass = 0; pass < 2; pass++) {
    const int qt = pass ? (NQT - 1 - bx) : bx;
    const int i0 = qt * 64;
    STAGEKV(0, 0);
    FragU qB[2];   // wave's 16 q-rows as B-operand
    {
      const bf16_t* qp = qk + base + (size_t)(i0 + w * 16 + ln) * DD;
      qB[0].v = *reinterpret_cast<const bf16x8*>(&qp[g * 8]);
      qB[1].v = *reinterpret_cast<const bf16x8*>(&qp[32 + g * 8]);
    }
    float m = -1e30f, lrow = 0.f;
    f32x4 acc[4] = {};
    const int iql = w * 16 + ln;

    for (int kt = 0; kt <= qt; kt++) {
      const int j0 = kt * 64;
      const int p = kt & 1;
      if (kt < qt) { STAGEKV(p ^ 1, j0 + 64); vmwait<4>(); }
      else vmwait<0>();
      barrier_raw();
      __builtin_amdgcn_sched_barrier(0);
      // S^T: sfr[nj] holds rows j = j0+nj*16+g*4+r, col i = i0+w*16+ln
      f32x4 sfr[4] = {};
#pragma unroll
      for (int ks = 0; ks < 2; ks++)
#pragma unroll
        for (int nj = 0; nj < 4; nj++) {
          int jc = nj * 16 + ln;
          FragU ka;
          ka.v = *reinterpret_cast<const bf16x8*>(&k_s[p][jc * 64 + (((ks * 4 + g) ^ (jc & 7)) * 8)]);
          sfr[nj] = __builtin_amdgcn_mfma_f32_16x16x32_bf16(ka.v, qB[ks].v, sfr[nj], 0, 0, 0);
        }
      if (kt == qt) {   // strictly-causal mask, diag tile only
#pragma unroll
        for (int nj = 0; nj < 4; nj++)
#pragma unroll
          for (int r = 0; r < 4; r++)
            if (nj * 16 + g * 4 + r >= iql) sfr[nj][r] = -1e30f;
      }
      float pm = -1e30f;
#pragma unroll
      for (int nj = 0; nj < 4; nj++)
#pragma unroll
        for (int r = 0; r < 4; r++) pm = fmaxf(pm, sfr[nj][r]);
      pm = fmaxf(pm, __shfl_xor(pm, 16, 64));
      pm = fmaxf(pm, __shfl_xor(pm, 32, 64));
      float mnew = fmaxf(m, pm);
      float fac = __expf(sc * (m - mnew));
      m = mnew;
      float ps = 0.f;
#pragma unroll
      for (int nj = 0; nj < 4; nj++)
#pragma unroll
        for (int r = 0; r < 4; r++) {
          float p2 = __expf(sc * (sfr[nj][r] - m));   // masked -> exp(-inf) = 0
          sfr[nj][r] = p2;
          ps += p2;
        }
      ps += __shfl_xor(ps, 16, 64);
      ps += __shfl_xor(ps, 32, 64);
      lrow = lrow * fac + ps;
      float facr[4];
#pragma unroll
      for (int r = 0; r < 4; r++) facr[r] = __shfl(fac, g * 4 + r, 64);
#pragma unroll
      for (int nd = 0; nd < 4; nd++)
#pragma unroll
        for (int r = 0; r < 4; r++) acc[nd][r] *= facr[r];
      // P fragments: A-operand layout == swapped-MFMA C layout (same lane)
      FragU pa[2];
#pragma unroll
      for (int js = 0; js < 2; js++)
#pragma unroll
        for (int kk = 0; kk < 4; kk++) {
          pa[js].v[kk]     = (bf16_t)sfr[js * 2][kk];
          pa[js].v[kk + 4] = (bf16_t)sfr[js * 2 + 1][kk];
        }
#pragma unroll
      for (int js = 0; js < 2; js++)
#pragma unroll
        for (int nd = 0; nd < 4; nd++) {
          int d = nd * 16 + ln;
          FragU vb;
          vb.v = *reinterpret_cast<const bf16x8*>(&v_t[p][d * 64 + (((js * 4 + g) ^ (d & 7)) * 8)]);
          acc[nd] = __builtin_amdgcn_mfma_f32_16x16x32_bf16(pa[js].v, vb.v, acc[nd], 0, 0, 0);
        }
      barrier_raw();   // all waves done reading buffer p -> next iter may restage it
    }
    float lr[4];
#pragma unroll
    for (int r = 0; r < 4; r++) lr[r] = __shfl(lrow, g * 4 + r, 64);
    const int orow0 = i0 + w * 16 + g * 4;
#pragma unroll
    for (int nd = 0; nd < 4; nd++) {
      const int colp = permk(nd * 16 + ln);
#pragma unroll
      for (int r = 0; r < 4; r++) {
        int grow = orow0 + r;
        float o = (grow > 0 && lr[r] > 0.f) ? acc[nd][r] / lr[r] : 0.f;  // row0 zero_pad
        outp[base + (size_t)grow * DD + colp] = (bf16_t)o;
      }
    }
  }
}

extern "C" void kernel_launch(void* const* d_in, const int* in_sizes, int n_in,
                              void* d_out, int out_size, void* d_ws, size_t ws_size,
                              hipStream_t stream) {
  const float* q_emb  = (const float*)d_in[0];
  const float* qa_emb = (const float*)d_in[1];
  const float* bfp    = (const float*)d_in[2];
  const float* Wk  = (const float*)d_in[3];
  const float* bk  = (const float*)d_in[4];
  const float* Wv  = (const float*)d_in[5];
  const float* bv  = (const float*)d_in[6];
  const float* Wo  = (const float*)d_in[7];
  const float* bo  = (const float*)d_in[8];
  const float* g1  = (const float*)d_in[9];
  const float* be1 = (const float*)d_in[10];
  const float* W1  = (const float*)d_in[11];
  const float* b1  = (const float*)d_in[12];
  const float* W2  = (const float*)d_in[13];
  const float* b2  = (const float*)d_in[14];
  const float* g2  = (const float*)d_in[15];
  const float* be2 = (const float*)d_in[16];
  float* out = (float*)d_out;
  (void)in_sizes; (void)n_in; (void)out_size; (void)ws_size;

  char* wsp = (char*)d_ws;
  size_t off = 0;
  auto alloc = [&](size_t bytes) -> void* {
    void* p = wsp + off;
    off += (bytes + 255) & ~(size_t)255;
    return p;
  };
  const size_t BSD = (size_t)BB * SS * DD;
  float*  pe   = (float*) alloc((size_t)SS * DD * 4);
  bf16_t* xb   = (bf16_t*)alloc(BSD * 2);
  bf16_t* yb   = (bf16_t*)alloc(BSD * 2);
  bf16_t* qkb  = (bf16_t*)alloc(BSD * 2);
  bf16_t* vtg  = (bf16_t*)alloc(BSD * 2);
  bf16_t* atb  = (bf16_t*)alloc(BSD * 2);
  bf16_t* tmpb = (bf16_t*)alloc(BSD * 2);
  bf16_t* h1   = (bf16_t*)alloc((size_t)BB * SS * FFD * 2);
  float*  g1p  = (float*) alloc((size_t)LL * DD * 4);
  float*  b1p  = (float*) alloc((size_t)LL * DD * 4);
  float*  g2p  = (float*) alloc((size_t)LL * DD * 4);
  float*  b2p  = (float*) alloc((size_t)LL * DD * 4);
  bf16_t* Wkb  = (bf16_t*)alloc((size_t)LL * DD * DD * 2);
  bf16_t* Wvb  = (bf16_t*)alloc((size_t)LL * DD * DD * 2);
  bf16_t* Wob  = (bf16_t*)alloc((size_t)LL * DD * DD * 2);
  bf16_t* W1b  = (bf16_t*)alloc((size_t)LL * DD * FFD * 2);
  bf16_t* W2b  = (bf16_t*)alloc((size_t)LL * FFD * DD * 2);

  pe_kernel<<<(SS * DD / 2 + 255) / 256, 256, 0, stream>>>(pe);
  gbperm_kernel<<<(LL * DD + 255) / 256, 256, 0, stream>>>(g1, be1, g2, be2, g1p, b1p, g2p, b2p);
  tcast_kernel<<<dim3(DD / 32, DD / 32, LL), 256, 0, stream>>>(Wk, Wkb, DD, DD);
  tcast_kernel<<<dim3(DD / 32, DD / 32, LL), 256, 0, stream>>>(Wv, Wvb, DD, DD);
  tcast_kernel<<<dim3(DD / 32, DD / 32, LL), 256, 0, stream>>>(Wo, Wob, DD, DD);
  tcast_kernel<<<dim3(FFD / 32, DD / 32, LL), 256, 0, stream>>>(W1, W1b, DD, FFD);
  tcast_kernel<<<dim3(DD / 32, FFD / 32, LL), 256, 0, stream>>>(W2, W2b, FFD, DD);
  addpe_kernel<<<(int)(BSD / 4 / 256), 256, 0, stream>>>(q_emb, qa_emb, pe, xb, yb);

  const int M = BB * SS;
  const int nD = (M / 128) * (DD / 128);     // 512 blocks (2-phase)
  const int nW = (M / 256) * (FFD / 256);    // 512 blocks (gemmW, FF1)
  dim3 gA(SS / 128, HH, BB);       // paired q-tiles
  for (int layer = 0; layer < LL; layer++) {
    const bf16_t* Wkl = Wkb + (size_t)layer * DD * DD;
    const bf16_t* Wvl = Wvb + (size_t)layer * DD * DD;
    const bf16_t* Wol = Wob + (size_t)layer * DD * DD;
    const bf16_t* W1l = W1b + (size_t)layer * DD * FFD;
    const bf16_t* W2l = W2b + (size_t)layer * FFD * DD;
    gemm_kernel<1, false><<<nD, 256, 0, stream>>>(xb, Wkl, bk + layer * DD, qkb, DD, DD, DD / 128);
    gemm_kernel<2, false><<<nD, 256, 0, stream>>>(yb, Wvl, bv + layer * DD, vtg, DD, DD, DD / 128);
    attn_kernel<<<gA, 256, 0, stream>>>(qkb, vtg, atb, bfp);
    gemm_kernel<1, false><<<nD, 256, 0, stream>>>(atb, Wol, bo + layer * DD, tmpb, DD, DD, DD / 128);
    lnp_kernel<false><<<M / 4, 256, 0, stream>>>(xb, tmpb, g1p + layer * DD, b1p + layer * DD, xb, nullptr);
    gemmW_kernel<<<nW, 512, 0, stream>>>(xb, W1l, b1 + layer * FFD, h1, FFD, DD, FFD / 256);
    gemm_kernel<1, false, true><<<nD, 256, 0, stream>>>(h1, W2l, b2 + layer * DD, tmpb, DD, FFD, DD / 128);
    if (layer == LL - 1)
      lnp_kernel<true><<<M / 4, 256, 0, stream>>>(xb, tmpb, g2p + layer * DD, b2p + layer * DD, nullptr, out);
    else
      lnp_kernel<false><<<M / 4, 256, 0, stream>>>(xb, tmpb, g2p + layer * DD, b2p + layer * DD, xb, nullptr);
  }
}

// Round 15
// 785.429 us; speedup vs baseline: 1.0371x; 1.0371x over previous
//
#include <hip/hip_runtime.h>
#include <hip/hip_bf16.h>

typedef __bf16 bf16_t;
typedef __bf16 bf16x4 __attribute__((ext_vector_type(4)));
typedef __bf16 bf16x8 __attribute__((ext_vector_type(8)));
typedef float f32x4 __attribute__((ext_vector_type(4)));

union FragU { bf16x8 v; bf16x4 h[2]; };
union F4U { float4 v; float f[4]; };

constexpr int BB = 32, SS = 512, DD = 512, FFD = 2048, LL = 4, HH = 8;

// Fragment-order permutation of k within each 32-elem chunk: granule order
// [0,4,1,5,2,6,3,7] -> MFMA fragment g is one contiguous 16B block.
__device__ __forceinline__ int permk(int k) {
  int g = (k >> 2) & 7;
  int pos = (g < 4) ? (g << 1) : (((g - 4) << 1) | 1);
  return (k & ~31) | (pos << 2) | (k & 3);
}
__device__ __forceinline__ int permpos(int c) {  // position of k (c=k&31) within chunk
  int gq = c >> 2;
  int pos = (gq < 4) ? (gq << 1) : (((gq - 4) << 1) | 1);
  return pos * 4 + (c & 3);
}

__device__ __forceinline__ void gload_lds16(const bf16_t* g, bf16_t* l) {
  __builtin_amdgcn_global_load_lds(
      (const __attribute__((address_space(1))) void*)g,
      (__attribute__((address_space(3))) void*)l, 16, 0, 0);
}

template<int N> __device__ __forceinline__ void vmwait() {
  asm volatile("s_waitcnt vmcnt(%0)" :: "n"(N) : "memory");
}
__device__ __forceinline__ void lgkmwait0() {
  asm volatile("s_waitcnt lgkmcnt(0)" ::: "memory");
}
__device__ __forceinline__ void barrier_raw() {
  asm volatile("s_barrier" ::: "memory");
}

#define MFMA_ACC(d, a, b) d = __builtin_amdgcn_mfma_f32_16x16x32_bf16((a).v, (b).v, d, 0, 0, 0)

// ---------------- positional-embedding table [S][D] ----------------
__global__ void pe_kernel(float* __restrict__ pe) {
  int idx = blockIdx.x * blockDim.x + threadIdx.x;  // pair index
  if (idx >= SS * DD / 2) return;
  int p = idx % (DD / 2);
  int s = idx / (DD / 2);
  float div = expf((float)(2 * p) * (-9.210340371976184f / (float)DD));
  float a = (float)s * div;
  pe[s * DD + 2 * p]     = sinf(a);
  pe[s * DD + 2 * p + 1] = cosf(a);
}

// ---------------- permute gamma/beta into permk order (per layer) ----------------
__global__ void gbperm_kernel(const float* __restrict__ g1, const float* __restrict__ b1,
                              const float* __restrict__ g2, const float* __restrict__ b2,
                              float* __restrict__ g1p, float* __restrict__ b1p,
                              float* __restrict__ g2p, float* __restrict__ b2p) {
  int idx = blockIdx.x * 256 + threadIdx.x;
  if (idx >= LL * DD) return;
  int p = (idx & ~511) | permk(idx & 511);
  g1p[p] = g1[idx]; b1p[p] = b1[idx]; g2p[p] = g2[idx]; b2p[p] = b2[idx];
}

// ---------------- transpose-cast: src [K][N] f32 -> dst [N][K]_perm bf16 ----
__global__ __launch_bounds__(256) void tcast_kernel(const float* __restrict__ src,
                                                    bf16_t* __restrict__ dst,
                                                    int K, int N) {
  __shared__ float tile[32][33];
  size_t mat = (size_t)blockIdx.z * (size_t)K * (size_t)N;
  int k0 = blockIdx.y * 32, n0 = blockIdx.x * 32;
  int t = threadIdx.x;
  int r = t >> 3, c4 = (t & 7) * 4;
  const float4 v = *reinterpret_cast<const float4*>(&src[mat + (size_t)(k0 + r) * N + n0 + c4]);
  tile[r][c4 + 0] = v.x; tile[r][c4 + 1] = v.y; tile[r][c4 + 2] = v.z; tile[r][c4 + 3] = v.w;
  __syncthreads();
  bf16x4 o;
  o[0] = (bf16_t)tile[c4 + 0][r];
  o[1] = (bf16_t)tile[c4 + 1][r];
  o[2] = (bf16_t)tile[c4 + 2][r];
  o[3] = (bf16_t)tile[c4 + 3][r];
  *reinterpret_cast<bf16x4*>(&dst[mat + permk((n0 + r) * K + k0 + c4)]) = o;
}

// ---------------- xb = bf16_perm(q + pe), yb = bf16_perm(qa + pe) ----------------
__global__ void addpe_kernel(const float* __restrict__ q, const float* __restrict__ qa,
                             const float* __restrict__ pe,
                             bf16_t* __restrict__ xb, bf16_t* __restrict__ yb) {
  int i = blockIdx.x * blockDim.x + threadIdx.x;  // float4 index
  int pei = i & (SS * DD / 4 - 1);
  float4 pv = reinterpret_cast<const float4*>(pe)[pei];
  float4 qv = reinterpret_cast<const float4*>(q)[i];
  float4 av = reinterpret_cast<const float4*>(qa)[i];
  bf16x4 xo, yo;
  xo[0] = (bf16_t)(qv.x + pv.x); xo[1] = (bf16_t)(qv.y + pv.y);
  xo[2] = (bf16_t)(qv.z + pv.z); xo[3] = (bf16_t)(qv.w + pv.w);
  yo[0] = (bf16_t)(av.x + pv.x); yo[1] = (bf16_t)(av.y + pv.y);
  yo[2] = (bf16_t)(av.z + pv.z); yo[3] = (bf16_t)(av.w + pv.w);
  int kp = permk(4 * i);
  *reinterpret_cast<bf16x4*>(&xb[kp]) = xo;
  *reinterpret_cast<bf16x4*>(&yb[kp]) = yo;
}

// ---------------- 2-phase GEMM: C[M,N] = A[M,K]_perm @ Bt[N,K]_perm^T + bias ----
// Counted-vmcnt double buffer (round-7 proven). OMODE: 1 = bf16 permk row-major,
// 2 = V^T attn layout (vtg). ATILED: A is in 256x256-tiled layout
// [m>>8][k>>8][m&255][perm(k&255)] (used for h1 in FF2).
template<int OMODE, bool RELU, bool ATILED = false>
__global__ __launch_bounds__(256, 2) void gemm_kernel(const bf16_t* __restrict__ A,
                                                      const bf16_t* __restrict__ Bt,
                                                      const float* __restrict__ bias,
                                                      void* __restrict__ Cout,
                                                      int N, int K, int nnt) {
  __shared__ bf16_t a_s[2][128 * 64];
  __shared__ bf16_t b_s[2][128 * 64];
  const int t = threadIdx.x;
  const int nwg = gridDim.x;
  const int bid = blockIdx.x;
  const int wg = (bid & 7) * (nwg >> 3) + (bid >> 3);   // bijective XCD swizzle
  const int m0 = (wg / nnt) * 128, n0 = (wg % nnt) * 128;
  const int l = t & 63, w = t >> 6, g = l >> 4, ln = l & 15;
  const int wm = (w >> 1) * 64, wn = (w & 1) * 64;
  const int tr = t >> 3;
  const int bsrc = ((t & 7) ^ (tr & 7)) * 8;
  const bf16_t* Asrc;
  size_t arstr;
  if constexpr (ATILED) {
    Asrc = A + (size_t)(m0 >> 8) * ((size_t)K * 256) + (size_t)((m0 & 255) + tr) * 256 + bsrc;
    arstr = 8192;   // 32 rows * 256
  } else {
    Asrc = A + (size_t)(m0 + tr) * K + bsrc;
    arstr = (size_t)32 * K;
  }
  const bf16_t* Bsrc = Bt + (size_t)(n0 + tr) * K + bsrc;
  const size_t rstr = (size_t)32 * K;
  const int x0 = (g ^ (ln & 7)) * 8;
  const int x1 = ((4 + g) ^ (ln & 7)) * 8;

  auto STAGE = [&](int p, int T) {
    const int ka = ATILED ? ((T >> 2) * 65536 + (T & 3) * 64) : (T << 6);
    const int kb = T << 6;
#pragma unroll
    for (int i = 0; i < 4; i++) gload_lds16(Asrc + ka + i * arstr, &a_s[p][(i * 256 + t) * 8]);
#pragma unroll
    for (int i = 0; i < 4; i++) gload_lds16(Bsrc + kb + i * rstr, &b_s[p][(i * 256 + t) * 8]);
  };

  f32x4 acc[4][4] = {};
  const int NT = K >> 6;
  STAGE(0, 0);
  STAGE(1, 1);
  for (int T = 0; T < NT; T++) {
    const int p = T & 1;
    if (T + 1 < NT) vmwait<8>(); else vmwait<0>();   // own tile-T loads landed
    barrier_raw();                                   // all waves' tile-T loads landed
    __builtin_amdgcn_sched_barrier(0);
#pragma unroll
    for (int kc = 0; kc < 2; kc++) {
      const int xo = kc ? x1 : x0;
      FragU fa[4], fb[4];
#pragma unroll
      for (int mi = 0; mi < 4; mi++)
        fa[mi].v = *reinterpret_cast<const bf16x8*>(&a_s[p][(wm + mi * 16 + ln) * 64 + xo]);
#pragma unroll
      for (int ni = 0; ni < 4; ni++)
        fb[ni].v = *reinterpret_cast<const bf16x8*>(&b_s[p][(wn + ni * 16 + ln) * 64 + xo]);
      __builtin_amdgcn_s_setprio(1);
#pragma unroll
      for (int mi = 0; mi < 4; mi++)
#pragma unroll
        for (int ni = 0; ni < 4; ni++)
          MFMA_ACC(acc[mi][ni], fa[mi], fb[ni]);
      __builtin_amdgcn_s_setprio(0);
    }
    __builtin_amdgcn_sched_barrier(0);
    barrier_raw();                                   // all waves done reading buffer p
    if (T + 2 < NT) STAGE(p, T + 2);                 // refill p; stays in flight
  }

  if constexpr (OMODE == 2) {
    const int brow = m0 >> 9;
    const int s0b = (m0 & 511) + wm;
    bf16_t* vout = reinterpret_cast<bf16_t*>(Cout);
#pragma unroll
    for (int ni = 0; ni < 4; ni++) {
      const int d = n0 + wn + ni * 16 + ln;
      const float bv = bias[d];
      const int h = d >> 6, dd = d & 63;
      bf16_t* vrow = vout + ((size_t)((brow * HH + h) * 64 + dd)) * SS;
#pragma unroll
      for (int mi = 0; mi < 4; mi++) {
        const int s0 = s0b + mi * 16 + g * 4;
        const int jt = s0 >> 6, jj = s0 & 63;
        const int js = jj >> 5, half = (jj >> 4) & 1;
        const int blkx = (js * 4 + g) ^ (dd & 7);
        bf16x4 o;
#pragma unroll
        for (int r = 0; r < 4; r++) o[r] = (bf16_t)(acc[mi][ni][r] + bv);
        *reinterpret_cast<bf16x4*>(&vrow[jt * 64 + blkx * 8 + half * 4]) = o;
      }
    }
  } else {
#pragma unroll
    for (int ni = 0; ni < 4; ni++) {
      const int col = n0 + wn + ni * 16 + ln;
      const float bv = bias[col];
      const int colp = permk(col);
#pragma unroll
      for (int mi = 0; mi < 4; mi++)
#pragma unroll
        for (int r = 0; r < 4; r++) {
          int row = m0 + wm + mi * 16 + g * 4 + r;
          float o = acc[mi][ni][r] + bv;
          if (RELU) o = fmaxf(o, 0.f);
          reinterpret_cast<bf16_t*>(Cout)[(size_t)row * N + colp] = (bf16_t)o;
        }
    }
  }
}

// ---------------- gemmW (FF1): R9 K-loop + LDS-staged epilogue (R8 construction) ----
// BM=BN=256, 8 waves (2Mx4N, wave=128x64); 4 phases, raw barriers, counted vmcnt(8).
// Epilogue: acc -> LDS image [128][256] (exact fit in a_s, block-XOR swizzle) ->
// fully-coalesced 16B stores into the block's own contiguous 128KB tile
// h1[m>>8][f>>8][m&255][perm(f&255)].
__global__ __launch_bounds__(512, 1) void gemmW_kernel(const bf16_t* __restrict__ A,
                                                       const bf16_t* __restrict__ Bt,
                                                       const float* __restrict__ bias,
                                                       bf16_t* __restrict__ Cout,
                                                       int N, int K, int nnt) {
  __shared__ bf16_t a_s[2][256 * 64];   // 64 KB
  __shared__ bf16_t b_s[2][256 * 64];   // 64 KB
  const int t = threadIdx.x;
  const int bid = blockIdx.x, nwg = gridDim.x;
  const int wg = (bid & 7) * (nwg >> 3) + (bid >> 3);
  const int m0 = (wg / nnt) * 256, n0 = (wg % nnt) * 256;
  const int l = t & 63, w = t >> 6, g = l >> 4, ln = l & 15, lnx = l & 7;
  const int wr = w >> 2, wc = w & 3;    // 2M x 4N wave grid; per-wave 128x64
  const int tr = t >> 3;
  const int bsrc = ((t & 7) ^ (tr & 7)) * 8;
  const bf16_t* Asrc = A + (size_t)(m0 + tr) * K + bsrc;
  const bf16_t* Bsrc = Bt + (size_t)(n0 + tr) * K + bsrc;
  const size_t rstr = (size_t)64 * K;
  const int x0 = (g ^ lnx) * 8;
  const int x1 = ((4 + g) ^ lnx) * 8;

  auto STA = [&](int q, int T2, int i) {
    gload_lds16(Asrc + (T2 << 6) + i * rstr, &a_s[q][(i * 512 + t) * 8]);
  };
  auto STB = [&](int q, int T2, int i) {
    gload_lds16(Bsrc + (T2 << 6) + i * rstr, &b_s[q][(i * 512 + t) * 8]);
  };

  f32x4 acc[8][4] = {};
  const int NT = K >> 6;
#pragma unroll
  for (int i = 0; i < 4; i++) { STA(0, 0, i); STB(0, 0, i); }
#pragma unroll
  for (int i = 0; i < 4; i++) { STA(1, 1, i); STB(1, 1, i); }
  vmwait<8>();
  barrier_raw();

  for (int T = 0; T < NT; T++) {
    const int p = T & 1;
    const bool st = (T + 2) < NT;
    FragU fa[4], fb[4];
    // ---- P0: A mh0 kc0 + B kc0 -> MFMA(mh0, kc0) ----
#pragma unroll
    for (int mf = 0; mf < 4; mf++)
      fa[mf].v = *reinterpret_cast<const bf16x8*>(&a_s[p][(wr * 128 + mf * 16 + ln) * 64 + x0]);
#pragma unroll
    for (int nf = 0; nf < 4; nf++)
      fb[nf].v = *reinterpret_cast<const bf16x8*>(&b_s[p][(wc * 64 + nf * 16 + ln) * 64 + x0]);
    barrier_raw();
    lgkmwait0();
    __builtin_amdgcn_sched_barrier(0);
    __builtin_amdgcn_s_setprio(1);
#pragma unroll
    for (int mf = 0; mf < 4; mf++)
#pragma unroll
      for (int nf = 0; nf < 4; nf++) MFMA_ACC(acc[mf][nf], fa[mf], fb[nf]);
    __builtin_amdgcn_s_setprio(0);
    barrier_raw();
    // ---- P1: A mh1 kc0 -> MFMA(mh1, kc0) ----
#pragma unroll
    for (int mf = 0; mf < 4; mf++)
      fa[mf].v = *reinterpret_cast<const bf16x8*>(&a_s[p][(wr * 128 + 64 + mf * 16 + ln) * 64 + x0]);
    barrier_raw();
    lgkmwait0();
    __builtin_amdgcn_sched_barrier(0);
    __builtin_amdgcn_s_setprio(1);
#pragma unroll
    for (int mf = 0; mf < 4; mf++)
#pragma unroll
      for (int nf = 0; nf < 4; nf++) MFMA_ACC(acc[4 + mf][nf], fa[mf], fb[nf]);
    __builtin_amdgcn_s_setprio(0);
    barrier_raw();
    // ---- P2: A mh0 kc1 + B kc1; stage A-rounds{0,2}+B (rows done being read) ----
#pragma unroll
    for (int mf = 0; mf < 4; mf++)
      fa[mf].v = *reinterpret_cast<const bf16x8*>(&a_s[p][(wr * 128 + mf * 16 + ln) * 64 + x1]);
#pragma unroll
    for (int nf = 0; nf < 4; nf++)
      fb[nf].v = *reinterpret_cast<const bf16x8*>(&b_s[p][(wc * 64 + nf * 16 + ln) * 64 + x1]);
    barrier_raw();
    if (st) { STA(p, T + 2, 0); STA(p, T + 2, 2); STB(p, T + 2, 0); STB(p, T + 2, 1); STB(p, T + 2, 2); STB(p, T + 2, 3); }
    lgkmwait0();
    __builtin_amdgcn_sched_barrier(0);
    __builtin_amdgcn_s_setprio(1);
#pragma unroll
    for (int mf = 0; mf < 4; mf++)
#pragma unroll
      for (int nf = 0; nf < 4; nf++) MFMA_ACC(acc[mf][nf], fa[mf], fb[nf]);
    __builtin_amdgcn_s_setprio(0);
    barrier_raw();
    // ---- P3: A mh1 kc1; stage A-rounds{1,3}; counted vmwait ----
#pragma unroll
    for (int mf = 0; mf < 4; mf++)
      fa[mf].v = *reinterpret_cast<const bf16x8*>(&a_s[p][(wr * 128 + 64 + mf * 16 + ln) * 64 + x1]);
    barrier_raw();
    if (st) { STA(p, T + 2, 1); STA(p, T + 2, 3); }
    lgkmwait0();
    __builtin_amdgcn_sched_barrier(0);
    __builtin_amdgcn_s_setprio(1);
#pragma unroll
    for (int mf = 0; mf < 4; mf++)
#pragma unroll
      for (int nf = 0; nf < 4; nf++) MFMA_ACC(acc[4 + mf][nf], fa[mf], fb[nf]);
    __builtin_amdgcn_s_setprio(0);
    if (T + 1 < NT) { if (st) vmwait<8>(); else vmwait<0>(); }
    barrier_raw();
  }

  // ---- LDS-staged epilogue: image [128][256] in a_s (exact fit), 2 half-passes.
  // Block-XOR swizzle blk ^ ((row>>2)&3) spreads g-groups across banks; readback
  // re-applies the XOR and stays fully coalesced (same 512B row, lanes permuted).
  const size_t tbase = (size_t)(m0 >> 8) * ((size_t)N * 256) + (size_t)(n0 >> 8) * 65536;
  bf16_t* img = &a_s[0][0];
  for (int hh = 0; hh < 2; hh++) {
    __syncthreads();
    if (wr == hh) {
#pragma unroll
      for (int nf = 0; nf < 4; nf++) {
        const int col_l = wc * 64 + nf * 16 + ln;
        const float bv = bias[n0 + col_l];
        const int colp = (col_l & ~31) | permpos(col_l & 31);
        const int cblk = colp >> 3, coff = colp & 7;
#pragma unroll
        for (int mf = 0; mf < 8; mf++)
#pragma unroll
          for (int r = 0; r < 4; r++) {
            int row = mf * 16 + g * 4 + r;
            int blkx = cblk ^ ((row >> 2) & 3);
            img[row * 256 + blkx * 8 + coff] = (bf16_t)fmaxf(acc[mf][nf][r] + bv, 0.f);
          }
      }
    }
    __syncthreads();
    const size_t obase = tbase + (size_t)(hh * 128) * 256;
#pragma unroll
    for (int rd = 0; rd < 8; rd++) {
      int idx = rd * 512 + t;
      int row = idx >> 5, c = idx & 31;
      bf16x8 v = *reinterpret_cast<const bf16x8*>(&img[row * 256 + c * 8]);
      int oc = c ^ ((row >> 2) & 3);
      *reinterpret_cast<bf16x8*>(&Cout[obase + (size_t)row * 256 + oc * 8]) = v;
    }
  }
}

// ---------------- residual + LayerNorm fully in permk-bf16 space ----------------
template<bool FINAL>
__global__ __launch_bounds__(256) void lnp_kernel(const bf16_t* __restrict__ xb,
                                                  const bf16_t* __restrict__ tb,
                                                  const float* __restrict__ gp,
                                                  const float* __restrict__ bp,
                                                  bf16_t* __restrict__ xbo,
                                                  float* __restrict__ fout) {
  int row = blockIdx.x * 4 + (threadIdx.x >> 6);
  int l = threadIdx.x & 63;
  size_t base = (size_t)row * DD + l * 8;
  FragU xv, tv;
  xv.v = *reinterpret_cast<const bf16x8*>(&xb[base]);
  tv.v = *reinterpret_cast<const bf16x8*>(&tb[base]);
  float vals[8];
  float s = 0.f;
#pragma unroll
  for (int j = 0; j < 8; j++) { vals[j] = (float)xv.v[j] + (float)tv.v[j]; s += vals[j]; }
#pragma unroll
  for (int off = 1; off < 64; off <<= 1) s += __shfl_xor(s, off, 64);
  float mean = s * (1.f / DD);
  float sq = 0.f;
#pragma unroll
  for (int j = 0; j < 8; j++) { float d = vals[j] - mean; sq += d * d; }
#pragma unroll
  for (int off = 1; off < 64; off <<= 1) sq += __shfl_xor(sq, off, 64);
  float rstd = rsqrtf(sq * (1.f / DD) + 1e-5f);
  F4U g0, g1q, b0, b1q;
  g0.v  = *reinterpret_cast<const float4*>(&gp[l * 8]);
  g1q.v = *reinterpret_cast<const float4*>(&gp[l * 8 + 4]);
  b0.v  = *reinterpret_cast<const float4*>(&bp[l * 8]);
  b1q.v = *reinterpret_cast<const float4*>(&bp[l * 8 + 4]);
  float ov[8];
#pragma unroll
  for (int j = 0; j < 4; j++) ov[j]     = (vals[j] - mean) * rstd * g0.f[j] + b0.f[j];
#pragma unroll
  for (int j = 0; j < 4; j++) ov[4 + j] = (vals[4 + j] - mean) * rstd * g1q.f[j] + b1q.f[j];
  if (FINAL) {
    int c = l >> 2, i = l & 3;
    F4U o0, o1;
#pragma unroll
    for (int j = 0; j < 4; j++) { o0.f[j] = ov[j]; o1.f[j] = ov[4 + j]; }
    float* fr = fout + (size_t)row * DD + c * 32 + 4 * i;
    *reinterpret_cast<float4*>(fr) = o0.v;
    *reinterpret_cast<float4*>(fr + 16) = o1.v;
  } else {
    FragU ob;
#pragma unroll
    for (int j = 0; j < 8; j++) ob.v[j] = (bf16_t)ov[j];
    *reinterpret_cast<bf16x8*>(&xbo[base]) = ob.v;
  }
}

// ---------------- fused causal attention, swapped-QK^T, dbuf K/V, counted vmcnt ----
__global__ __launch_bounds__(256) void attn_kernel(const bf16_t* __restrict__ qk,
                                                   const bf16_t* __restrict__ vtg,
                                                   bf16_t* __restrict__ outp,
                                                   const float* __restrict__ bfp) {
  __shared__ bf16_t k_s[2][64 * 64];   // K tiles, block-XOR pre-swizzled via source
  __shared__ bf16_t v_t[2][64 * 64];   // V^T tiles, swizzle baked in global layout
  const int bx = blockIdx.x, h = blockIdx.y, b = blockIdx.z;
  const int t = threadIdx.x, l = t & 63, w = t >> 6, g = l >> 4, ln = l & 15;
  const float sc = 0.125f * (1.f + bfp[0]);
  const size_t base = ((size_t)b * SS) * DD + h * 64;
  const bf16_t* vbase = vtg + ((size_t)((b * HH + h) * 64)) * SS;
  const int NQT = SS / 64;

  auto STAGEKV = [&](int q, int j0) {
    int c1 = t + 256;
    int jr0 = t >> 3, bb0 = t & 7;
    int jr1 = c1 >> 3, bb1 = c1 & 7;
    gload_lds16(qk + base + (size_t)(j0 + jr0) * DD + ((bb0 ^ (jr0 & 7)) * 8), &k_s[q][t * 8]);
    gload_lds16(qk + base + (size_t)(j0 + jr1) * DD + ((bb1 ^ (jr1 & 7)) * 8), &k_s[q][c1 * 8]);
    gload_lds16(vbase + (size_t)jr0 * SS + j0 + bb0 * 8, &v_t[q][t * 8]);
    gload_lds16(vbase + (size_t)jr1 * SS + j0 + bb1 * 8, &v_t[q][c1 * 8]);
  };

  for (int pass = 0; pass < 2; pass++) {
    const int qt = pass ? (NQT - 1 - bx) : bx;
    const int i0 = qt * 64;
    STAGEKV(0, 0);
    FragU qB[2];   // wave's 16 q-rows as B-operand
    {
      const bf16_t* qp = qk + base + (size_t)(i0 + w * 16 + ln) * DD;
      qB[0].v = *reinterpret_cast<const bf16x8*>(&qp[g * 8]);
      qB[1].v = *reinterpret_cast<const bf16x8*>(&qp[32 + g * 8]);
    }
    float m = -1e30f, lrow = 0.f;
    f32x4 acc[4] = {};
    const int iql = w * 16 + ln;

    for (int kt = 0; kt <= qt; kt++) {
      const int j0 = kt * 64;
      const int p = kt & 1;
      if (kt < qt) { STAGEKV(p ^ 1, j0 + 64); vmwait<4>(); }
      else vmwait<0>();
      barrier_raw();
      __builtin_amdgcn_sched_barrier(0);
      // S^T: sfr[nj] holds rows j = j0+nj*16+g*4+r, col i = i0+w*16+ln
      f32x4 sfr[4] = {};
#pragma unroll
      for (int ks = 0; ks < 2; ks++)
#pragma unroll
        for (int nj = 0; nj < 4; nj++) {
          int jc = nj * 16 + ln;
          FragU ka;
          ka.v = *reinterpret_cast<const bf16x8*>(&k_s[p][jc * 64 + (((ks * 4 + g) ^ (jc & 7)) * 8)]);
          sfr[nj] = __builtin_amdgcn_mfma_f32_16x16x32_bf16(ka.v, qB[ks].v, sfr[nj], 0, 0, 0);
        }
      if (kt == qt) {   // strictly-causal mask, diag tile only
#pragma unroll
        for (int nj = 0; nj < 4; nj++)
#pragma unroll
          for (int r = 0; r < 4; r++)
            if (nj * 16 + g * 4 + r >= iql) sfr[nj][r] = -1e30f;
      }
      float pm = -1e30f;
#pragma unroll
      for (int nj = 0; nj < 4; nj++)
#pragma unroll
        for (int r = 0; r < 4; r++) pm = fmaxf(pm, sfr[nj][r]);
      pm = fmaxf(pm, __shfl_xor(pm, 16, 64));
      pm = fmaxf(pm, __shfl_xor(pm, 32, 64));
      float mnew = fmaxf(m, pm);
      float fac = __expf(sc * (m - mnew));
      m = mnew;
      float ps = 0.f;
#pragma unroll
      for (int nj = 0; nj < 4; nj++)
#pragma unroll
        for (int r = 0; r < 4; r++) {
          float p2 = __expf(sc * (sfr[nj][r] - m));   // masked -> exp(-inf) = 0
          sfr[nj][r] = p2;
          ps += p2;
        }
      ps += __shfl_xor(ps, 16, 64);
      ps += __shfl_xor(ps, 32, 64);
      lrow = lrow * fac + ps;
      float facr[4];
#pragma unroll
      for (int r = 0; r < 4; r++) facr[r] = __shfl(fac, g * 4 + r, 64);
#pragma unroll
      for (int nd = 0; nd < 4; nd++)
#pragma unroll
        for (int r = 0; r < 4; r++) acc[nd][r] *= facr[r];
      // P fragments: A-operand layout == swapped-MFMA C layout (same lane)
      FragU pa[2];
#pragma unroll
      for (int js = 0; js < 2; js++)
#pragma unroll
        for (int kk = 0; kk < 4; kk++) {
          pa[js].v[kk]     = (bf16_t)sfr[js * 2][kk];
          pa[js].v[kk + 4] = (bf16_t)sfr[js * 2 + 1][kk];
        }
#pragma unroll
      for (int js = 0; js < 2; js++)
#pragma unroll
        for (int nd = 0; nd < 4; nd++) {
          int d = nd * 16 + ln;
          FragU vb;
          vb.v = *reinterpret_cast<const bf16x8*>(&v_t[p][d * 64 + (((js * 4 + g) ^ (d & 7)) * 8)]);
          acc[nd] = __builtin_amdgcn_mfma_f32_16x16x32_bf16(pa[js].v, vb.v, acc[nd], 0, 0, 0);
        }
      barrier_raw();   // all waves done reading buffer p -> next iter may restage it
    }
    float lr[4];
#pragma unroll
    for (int r = 0; r < 4; r++) lr[r] = __shfl(lrow, g * 4 + r, 64);
    const int orow0 = i0 + w * 16 + g * 4;
#pragma unroll
    for (int nd = 0; nd < 4; nd++) {
      const int colp = permk(nd * 16 + ln);
#pragma unroll
      for (int r = 0; r < 4; r++) {
        int grow = orow0 + r;
        float o = (grow > 0 && lr[r] > 0.f) ? acc[nd][r] / lr[r] : 0.f;  // row0 zero_pad
        outp[base + (size_t)grow * DD + colp] = (bf16_t)o;
      }
    }
  }
}

extern "C" void kernel_launch(void* const* d_in, const int* in_sizes, int n_in,
                              void* d_out, int out_size, void* d_ws, size_t ws_size,
                              hipStream_t stream) {
  const float* q_emb  = (const float*)d_in[0];
  const float* qa_emb = (const float*)d_in[1];
  const float* bfp    = (const float*)d_in[2];
  const float* Wk  = (const float*)d_in[3];
  const float* bk  = (const float*)d_in[4];
  const float* Wv  = (const float*)d_in[5];
  const float* bv  = (const float*)d_in[6];
  const float* Wo  = (const float*)d_in[7];
  const float* bo  = (const float*)d_in[8];
  const float* g1  = (const float*)d_in[9];
  const float* be1 = (const float*)d_in[10];
  const float* W1  = (const float*)d_in[11];
  const float* b1  = (const float*)d_in[12];
  const float* W2  = (const float*)d_in[13];
  const float* b2  = (const float*)d_in[14];
  const float* g2  = (const float*)d_in[15];
  const float* be2 = (const float*)d_in[16];
  float* out = (float*)d_out;
  (void)in_sizes; (void)n_in; (void)out_size; (void)ws_size;

  char* wsp = (char*)d_ws;
  size_t off = 0;
  auto alloc = [&](size_t bytes) -> void* {
    void* p = wsp + off;
    off += (bytes + 255) & ~(size_t)255;
    return p;
  };
  const size_t BSD = (size_t)BB * SS * DD;
  float*  pe   = (float*) alloc((size_t)SS * DD * 4);
  bf16_t* xb   = (bf16_t*)alloc(BSD * 2);
  bf16_t* yb   = (bf16_t*)alloc(BSD * 2);
  bf16_t* qkb  = (bf16_t*)alloc(BSD * 2);
  bf16_t* vtg  = (bf16_t*)alloc(BSD * 2);
  bf16_t* atb  = (bf16_t*)alloc(BSD * 2);
  bf16_t* tmpb = (bf16_t*)alloc(BSD * 2);
  bf16_t* h1   = (bf16_t*)alloc((size_t)BB * SS * FFD * 2);
  float*  g1p  = (float*) alloc((size_t)LL * DD * 4);
  float*  b1p  = (float*) alloc((size_t)LL * DD * 4);
  float*  g2p  = (float*) alloc((size_t)LL * DD * 4);
  float*  b2p  = (float*) alloc((size_t)LL * DD * 4);
  bf16_t* Wkb  = (bf16_t*)alloc((size_t)LL * DD * DD * 2);
  bf16_t* Wvb  = (bf16_t*)alloc((size_t)LL * DD * DD * 2);
  bf16_t* Wob  = (bf16_t*)alloc((size_t)LL * DD * DD * 2);
  bf16_t* W1b  = (bf16_t*)alloc((size_t)LL * DD * FFD * 2);
  bf16_t* W2b  = (bf16_t*)alloc((size_t)LL * FFD * DD * 2);

  pe_kernel<<<(SS * DD / 2 + 255) / 256, 256, 0, stream>>>(pe);
  gbperm_kernel<<<(LL * DD + 255) / 256, 256, 0, stream>>>(g1, be1, g2, be2, g1p, b1p, g2p, b2p);
  tcast_kernel<<<dim3(DD / 32, DD / 32, LL), 256, 0, stream>>>(Wk, Wkb, DD, DD);
  tcast_kernel<<<dim3(DD / 32, DD / 32, LL), 256, 0, stream>>>(Wv, Wvb, DD, DD);
  tcast_kernel<<<dim3(DD / 32, DD / 32, LL), 256, 0, stream>>>(Wo, Wob, DD, DD);
  tcast_kernel<<<dim3(FFD / 32, DD / 32, LL), 256, 0, stream>>>(W1, W1b, DD, FFD);
  tcast_kernel<<<dim3(DD / 32, FFD / 32, LL), 256, 0, stream>>>(W2, W2b, FFD, DD);
  addpe_kernel<<<(int)(BSD / 4 / 256), 256, 0, stream>>>(q_emb, qa_emb, pe, xb, yb);

  const int M = BB * SS;
  const int nD = (M / 128) * (DD / 128);     // 512 blocks (2-phase)
  const int nW = (M / 256) * (FFD / 256);    // 512 blocks (gemmW, FF1)
  dim3 gA(SS / 128, HH, BB);       // paired q-tiles
  for (int layer = 0; layer < LL; layer++) {
    const bf16_t* Wkl = Wkb + (size_t)layer * DD * DD;
    const bf16_t* Wvl = Wvb + (size_t)layer * DD * DD;
    const bf16_t* Wol = Wob + (size_t)layer * DD * DD;
    const bf16_t* W1l = W1b + (size_t)layer * DD * FFD;
    const bf16_t* W2l = W2b + (size_t)layer * FFD * DD;
    gemm_kernel<1, false><<<nD, 256, 0, stream>>>(xb, Wkl, bk + layer * DD, qkb, DD, DD, DD / 128);
    gemm_kernel<2, false><<<nD, 256, 0, stream>>>(yb, Wvl, bv + layer * DD, vtg, DD, DD, DD / 128);
    attn_kernel<<<gA, 256, 0, stream>>>(qkb, vtg, atb, bfp);
    gemm_kernel<1, false><<<nD, 256, 0, stream>>>(atb, Wol, bo + layer * DD, tmpb, DD, DD, DD / 128);
    lnp_kernel<false><<<M / 4, 256, 0, stream>>>(xb, tmpb, g1p + layer * DD, b1p + layer * DD, xb, nullptr);
    gemmW_kernel<<<nW, 512, 0, stream>>>(xb, W1l, b1 + layer * FFD, h1, FFD, DD, FFD / 256);
    gemm_kernel<1, false, true><<<nD, 256, 0, stream>>>(h1, W2l, b2 + layer * DD, tmpb, DD, FFD, DD / 128);
    if (layer == LL - 1)
      lnp_kernel<true><<<M / 4, 256, 0, stream>>>(xb, tmpb, g2p + layer * DD, b2p + layer * DD, nullptr, out);
    else
      lnp_kernel<false><<<M / 4, 256, 0, stream>>>(xb, tmpb, g2p + layer * DD, b2p + layer * DD, xb, nullptr);
  }
}

// Round 16
// 741.872 us; speedup vs baseline: 1.0979x; 1.0587x over previous
//
#include <hip/hip_runtime.h>
#include <hip/hip_bf16.h>

typedef __bf16 bf16_t;
typedef __bf16 bf16x4 __attribute__((ext_vector_type(4)));
typedef __bf16 bf16x8 __attribute__((ext_vector_type(8)));
typedef float f32x4 __attribute__((ext_vector_type(4)));

union FragU { bf16x8 v; bf16x4 h[2]; };
union F4U { float4 v; float f[4]; };

constexpr int BB = 32, SS = 512, DD = 512, FFD = 2048, LL = 4, HH = 8;

// Fragment-order permutation of k within each 32-elem chunk: granule order
// [0,4,1,5,2,6,3,7] -> MFMA fragment g is one contiguous 16B block.
__device__ __forceinline__ int permk(int k) {
  int g = (k >> 2) & 7;
  int pos = (g < 4) ? (g << 1) : (((g - 4) << 1) | 1);
  return (k & ~31) | (pos << 2) | (k & 3);
}

__device__ __forceinline__ void gload_lds16(const bf16_t* g, bf16_t* l) {
  __builtin_amdgcn_global_load_lds(
      (const __attribute__((address_space(1))) void*)g,
      (__attribute__((address_space(3))) void*)l, 16, 0, 0);
}

template<int N> __device__ __forceinline__ void vmwait() {
  asm volatile("s_waitcnt vmcnt(%0)" :: "n"(N) : "memory");
}
__device__ __forceinline__ void barrier_raw() {
  asm volatile("s_barrier" ::: "memory");
}

#define MFMA_ACC(d, a, b) d = __builtin_amdgcn_mfma_f32_16x16x32_bf16((a).v, (b).v, d, 0, 0, 0)

// ---------------- positional-embedding table [S][D] ----------------
__global__ void pe_kernel(float* __restrict__ pe) {
  int idx = blockIdx.x * blockDim.x + threadIdx.x;  // pair index
  if (idx >= SS * DD / 2) return;
  int p = idx % (DD / 2);
  int s = idx / (DD / 2);
  float div = expf((float)(2 * p) * (-9.210340371976184f / (float)DD));
  float a = (float)s * div;
  pe[s * DD + 2 * p]     = sinf(a);
  pe[s * DD + 2 * p + 1] = cosf(a);
}

// ---------------- permute gamma/beta into permk order (per layer) ----------------
__global__ void gbperm_kernel(const float* __restrict__ g1, const float* __restrict__ b1,
                              const float* __restrict__ g2, const float* __restrict__ b2,
                              float* __restrict__ g1p, float* __restrict__ b1p,
                              float* __restrict__ g2p, float* __restrict__ b2p) {
  int idx = blockIdx.x * 256 + threadIdx.x;
  if (idx >= LL * DD) return;
  int p = (idx & ~511) | permk(idx & 511);
  g1p[p] = g1[idx]; b1p[p] = b1[idx]; g2p[p] = g2[idx]; b2p[p] = b2[idx];
}

// ---------------- transpose-cast: src [K][N] f32 -> dst [N][K]_perm bf16 ----
__global__ __launch_bounds__(256) void tcast_kernel(const float* __restrict__ src,
                                                    bf16_t* __restrict__ dst,
                                                    int K, int N) {
  __shared__ float tile[32][33];
  size_t mat = (size_t)blockIdx.z * (size_t)K * (size_t)N;
  int k0 = blockIdx.y * 32, n0 = blockIdx.x * 32;
  int t = threadIdx.x;
  int r = t >> 3, c4 = (t & 7) * 4;
  const float4 v = *reinterpret_cast<const float4*>(&src[mat + (size_t)(k0 + r) * N + n0 + c4]);
  tile[r][c4 + 0] = v.x; tile[r][c4 + 1] = v.y; tile[r][c4 + 2] = v.z; tile[r][c4 + 3] = v.w;
  __syncthreads();
  bf16x4 o;
  o[0] = (bf16_t)tile[c4 + 0][r];
  o[1] = (bf16_t)tile[c4 + 1][r];
  o[2] = (bf16_t)tile[c4 + 2][r];
  o[3] = (bf16_t)tile[c4 + 3][r];
  *reinterpret_cast<bf16x4*>(&dst[mat + permk((n0 + r) * K + k0 + c4)]) = o;
}

// ---------------- xb = bf16_perm(q + pe), yb = bf16_perm(qa + pe) ----------------
__global__ void addpe_kernel(const float* __restrict__ q, const float* __restrict__ qa,
                             const float* __restrict__ pe,
                             bf16_t* __restrict__ xb, bf16_t* __restrict__ yb) {
  int i = blockIdx.x * blockDim.x + threadIdx.x;  // float4 index
  int pei = i & (SS * DD / 4 - 1);
  float4 pv = reinterpret_cast<const float4*>(pe)[pei];
  float4 qv = reinterpret_cast<const float4*>(q)[i];
  float4 av = reinterpret_cast<const float4*>(qa)[i];
  bf16x4 xo, yo;
  xo[0] = (bf16_t)(qv.x + pv.x); xo[1] = (bf16_t)(qv.y + pv.y);
  xo[2] = (bf16_t)(qv.z + pv.z); xo[3] = (bf16_t)(qv.w + pv.w);
  yo[0] = (bf16_t)(av.x + pv.x); yo[1] = (bf16_t)(av.y + pv.y);
  yo[2] = (bf16_t)(av.z + pv.z); yo[3] = (bf16_t)(av.w + pv.w);
  int kp = permk(4 * i);
  *reinterpret_cast<bf16x4*>(&xb[kp]) = xo;
  *reinterpret_cast<bf16x4*>(&yb[kp]) = yo;
}

// ---------------- 2-phase GEMM: C[M,N] = A[M,K]_perm @ Bt[N,K]_perm^T + bias ----
// Counted-vmcnt double buffer (round-7 proven). OMODE: 1 = bf16 permk row-major,
// 2 = V^T attn layout, batched over layers (Bt rows 0..LL*DD, layer = d>>9).
template<int OMODE, bool RELU>
__global__ __launch_bounds__(256, 2) void gemm_kernel(const bf16_t* __restrict__ A,
                                                      const bf16_t* __restrict__ Bt,
                                                      const float* __restrict__ bias,
                                                      void* __restrict__ Cout,
                                                      int N, int K, int nnt) {
  __shared__ bf16_t a_s[2][128 * 64];
  __shared__ bf16_t b_s[2][128 * 64];
  const int t = threadIdx.x;
  const int nwg = gridDim.x;
  const int bid = blockIdx.x;
  const int wg = (bid & 7) * (nwg >> 3) + (bid >> 3);   // bijective XCD swizzle
  const int m0 = (wg / nnt) * 128, n0 = (wg % nnt) * 128;
  const int l = t & 63, w = t >> 6, g = l >> 4, ln = l & 15;
  const int wm = (w >> 1) * 64, wn = (w & 1) * 64;
  const int tr = t >> 3;
  const int bsrc = ((t & 7) ^ (tr & 7)) * 8;
  const bf16_t* Asrc = A + (size_t)(m0 + tr) * K + bsrc;
  const bf16_t* Bsrc = Bt + (size_t)(n0 + tr) * K + bsrc;
  const size_t rstr = (size_t)32 * K;
  const int x0 = (g ^ (ln & 7)) * 8;
  const int x1 = ((4 + g) ^ (ln & 7)) * 8;

  auto STAGE = [&](int p, int T) {
    const int k0 = T << 6;
#pragma unroll
    for (int i = 0; i < 4; i++) gload_lds16(Asrc + k0 + i * rstr, &a_s[p][(i * 256 + t) * 8]);
#pragma unroll
    for (int i = 0; i < 4; i++) gload_lds16(Bsrc + k0 + i * rstr, &b_s[p][(i * 256 + t) * 8]);
  };

  f32x4 acc[4][4] = {};
  const int NT = K >> 6;
  STAGE(0, 0);
  STAGE(1, 1);
  for (int T = 0; T < NT; T++) {
    const int p = T & 1;
    if (T + 1 < NT) vmwait<8>(); else vmwait<0>();   // own tile-T loads landed
    barrier_raw();                                   // all waves' tile-T loads landed
    __builtin_amdgcn_sched_barrier(0);
#pragma unroll
    for (int kc = 0; kc < 2; kc++) {
      const int xo = kc ? x1 : x0;
      FragU fa[4], fb[4];
#pragma unroll
      for (int mi = 0; mi < 4; mi++)
        fa[mi].v = *reinterpret_cast<const bf16x8*>(&a_s[p][(wm + mi * 16 + ln) * 64 + xo]);
#pragma unroll
      for (int ni = 0; ni < 4; ni++)
        fb[ni].v = *reinterpret_cast<const bf16x8*>(&b_s[p][(wn + ni * 16 + ln) * 64 + xo]);
      __builtin_amdgcn_s_setprio(1);
#pragma unroll
      for (int mi = 0; mi < 4; mi++)
#pragma unroll
        for (int ni = 0; ni < 4; ni++)
          MFMA_ACC(acc[mi][ni], fa[mi], fb[ni]);
      __builtin_amdgcn_s_setprio(0);
    }
    __builtin_amdgcn_sched_barrier(0);
    barrier_raw();                                   // all waves done reading buffer p
    if (T + 2 < NT) STAGE(p, T + 2);                 // refill p; stays in flight
  }

  if constexpr (OMODE == 2) {
    const int brow = m0 >> 9;
    const int s0b = (m0 & 511) + wm;
    bf16_t* vout = reinterpret_cast<bf16_t*>(Cout);
#pragma unroll
    for (int ni = 0; ni < 4; ni++) {
      const int d = n0 + wn + ni * 16 + ln;
      const float bv = bias[d];
      const int layer = d >> 9;            // batched over layers
      const int h = (d >> 6) & 7, dd = d & 63;
      bf16_t* vrow = vout + (size_t)layer * ((size_t)BB * SS * DD) +
                     ((size_t)((brow * HH + h) * 64 + dd)) * SS;
#pragma unroll
      for (int mi = 0; mi < 4; mi++) {
        const int s0 = s0b + mi * 16 + g * 4;
        const int jt = s0 >> 6, jj = s0 & 63;
        const int js = jj >> 5, half = (jj >> 4) & 1;
        const int blkx = (js * 4 + g) ^ (dd & 7);
        bf16x4 o;
#pragma unroll
        for (int r = 0; r < 4; r++) o[r] = (bf16_t)(acc[mi][ni][r] + bv);
        *reinterpret_cast<bf16x4*>(&vrow[jt * 64 + blkx * 8 + half * 4]) = o;
      }
    }
  } else {
#pragma unroll
    for (int ni = 0; ni < 4; ni++) {
      const int col = n0 + wn + ni * 16 + ln;
      const float bv = bias[col];
      const int colp = permk(col);
#pragma unroll
      for (int mi = 0; mi < 4; mi++)
#pragma unroll
        for (int r = 0; r < 4; r++) {
          int row = m0 + wm + mi * 16 + g * 4 + r;
          float o = acc[mi][ni][r] + bv;
          if (RELU) o = fmaxf(o, 0.f);
          reinterpret_cast<bf16_t*>(Cout)[(size_t)row * N + colp] = (bf16_t)o;
        }
    }
  }
}

// ---------------- residual + LayerNorm fully in permk-bf16 space ----------------
template<bool FINAL>
__global__ __launch_bounds__(256) void lnp_kernel(const bf16_t* __restrict__ xb,
                                                  const bf16_t* __restrict__ tb,
                                                  const float* __restrict__ gp,
                                                  const float* __restrict__ bp,
                                                  bf16_t* __restrict__ xbo,
                                                  float* __restrict__ fout) {
  int row = blockIdx.x * 4 + (threadIdx.x >> 6);
  int l = threadIdx.x & 63;
  size_t base = (size_t)row * DD + l * 8;
  FragU xv, tv;
  xv.v = *reinterpret_cast<const bf16x8*>(&xb[base]);
  tv.v = *reinterpret_cast<const bf16x8*>(&tb[base]);
  float vals[8];
  float s = 0.f;
#pragma unroll
  for (int j = 0; j < 8; j++) { vals[j] = (float)xv.v[j] + (float)tv.v[j]; s += vals[j]; }
#pragma unroll
  for (int off = 1; off < 64; off <<= 1) s += __shfl_xor(s, off, 64);
  float mean = s * (1.f / DD);
  float sq = 0.f;
#pragma unroll
  for (int j = 0; j < 8; j++) { float d = vals[j] - mean; sq += d * d; }
#pragma unroll
  for (int off = 1; off < 64; off <<= 1) sq += __shfl_xor(sq, off, 64);
  float rstd = rsqrtf(sq * (1.f / DD) + 1e-5f);
  F4U g0, g1q, b0, b1q;
  g0.v  = *reinterpret_cast<const float4*>(&gp[l * 8]);
  g1q.v = *reinterpret_cast<const float4*>(&gp[l * 8 + 4]);
  b0.v  = *reinterpret_cast<const float4*>(&bp[l * 8]);
  b1q.v = *reinterpret_cast<const float4*>(&bp[l * 8 + 4]);
  float ov[8];
#pragma unroll
  for (int j = 0; j < 4; j++) ov[j]     = (vals[j] - mean) * rstd * g0.f[j] + b0.f[j];
#pragma unroll
  for (int j = 0; j < 4; j++) ov[4 + j] = (vals[4 + j] - mean) * rstd * g1q.f[j] + b1q.f[j];
  if (FINAL) {
    int c = l >> 2, i = l & 3;
    F4U o0, o1;
#pragma unroll
    for (int j = 0; j < 4; j++) { o0.f[j] = ov[j]; o1.f[j] = ov[4 + j]; }
    float* fr = fout + (size_t)row * DD + c * 32 + 4 * i;
    *reinterpret_cast<float4*>(fr) = o0.v;
    *reinterpret_cast<float4*>(fr + 16) = o1.v;
  } else {
    FragU ob;
#pragma unroll
    for (int j = 0; j < 8; j++) ob.v[j] = (bf16_t)ov[j];
    *reinterpret_cast<bf16x8*>(&xbo[base]) = ob.v;
  }
}

// ---------------- fused causal attention, swapped-QK^T, dbuf K/V, counted vmcnt ----
__global__ __launch_bounds__(256) void attn_kernel(const bf16_t* __restrict__ qk,
                                                   const bf16_t* __restrict__ vtg,
                                                   bf16_t* __restrict__ outp,
                                                   const float* __restrict__ bfp) {
  __shared__ bf16_t k_s[2][64 * 64];   // K tiles, block-XOR pre-swizzled via source
  __shared__ bf16_t v_t[2][64 * 64];   // V^T tiles, swizzle baked in global layout
  const int bx = blockIdx.x, h = blockIdx.y, b = blockIdx.z;
  const int t = threadIdx.x, l = t & 63, w = t >> 6, g = l >> 4, ln = l & 15;
  const float sc = 0.125f * (1.f + bfp[0]);
  const size_t base = ((size_t)b * SS) * DD + h * 64;
  const bf16_t* vbase = vtg + ((size_t)((b * HH + h) * 64)) * SS;
  const int NQT = SS / 64;

  auto STAGEKV = [&](int q, int j0) {
    int c1 = t + 256;
    int jr0 = t >> 3, bb0 = t & 7;
    int jr1 = c1 >> 3, bb1 = c1 & 7;
    gload_lds16(qk + base + (size_t)(j0 + jr0) * DD + ((bb0 ^ (jr0 & 7)) * 8), &k_s[q][t * 8]);
    gload_lds16(qk + base + (size_t)(j0 + jr1) * DD + ((bb1 ^ (jr1 & 7)) * 8), &k_s[q][c1 * 8]);
    gload_lds16(vbase + (size_t)jr0 * SS + j0 + bb0 * 8, &v_t[q][t * 8]);
    gload_lds16(vbase + (size_t)jr1 * SS + j0 + bb1 * 8, &v_t[q][c1 * 8]);
  };

  for (int pass = 0; pass < 2; pass++) {
    const int qt = pass ? (NQT - 1 - bx) : bx;
    const int i0 = qt * 64;
    STAGEKV(0, 0);
    FragU qB[2];   // wave's 16 q-rows as B-operand
    {
      const bf16_t* qp = qk + base + (size_t)(i0 + w * 16 + ln) * DD;
      qB[0].v = *reinterpret_cast<const bf16x8*>(&qp[g * 8]);
      qB[1].v = *reinterpret_cast<const bf16x8*>(&qp[32 + g * 8]);
    }
    float m = -1e30f, lrow = 0.f;
    f32x4 acc[4] = {};
    const int iql = w * 16 + ln;

    for (int kt = 0; kt <= qt; kt++) {
      const int j0 = kt * 64;
      const int p = kt & 1;
      if (kt < qt) { STAGEKV(p ^ 1, j0 + 64); vmwait<4>(); }
      else vmwait<0>();
      barrier_raw();
      __builtin_amdgcn_sched_barrier(0);
      // S^T: sfr[nj] holds rows j = j0+nj*16+g*4+r, col i = i0+w*16+ln
      f32x4 sfr[4] = {};
#pragma unroll
      for (int ks = 0; ks < 2; ks++)
#pragma unroll
        for (int nj = 0; nj < 4; nj++) {
          int jc = nj * 16 + ln;
          FragU ka;
          ka.v = *reinterpret_cast<const bf16x8*>(&k_s[p][jc * 64 + (((ks * 4 + g) ^ (jc & 7)) * 8)]);
          sfr[nj] = __builtin_amdgcn_mfma_f32_16x16x32_bf16(ka.v, qB[ks].v, sfr[nj], 0, 0, 0);
        }
      if (kt == qt) {   // strictly-causal mask, diag tile only
#pragma unroll
        for (int nj = 0; nj < 4; nj++)
#pragma unroll
          for (int r = 0; r < 4; r++)
            if (nj * 16 + g * 4 + r >= iql) sfr[nj][r] = -1e30f;
      }
      float pm = -1e30f;
#pragma unroll
      for (int nj = 0; nj < 4; nj++)
#pragma unroll
        for (int r = 0; r < 4; r++) pm = fmaxf(pm, sfr[nj][r]);
      pm = fmaxf(pm, __shfl_xor(pm, 16, 64));
      pm = fmaxf(pm, __shfl_xor(pm, 32, 64));
      float mnew = fmaxf(m, pm);
      float fac = __expf(sc * (m - mnew));
      m = mnew;
      float ps = 0.f;
#pragma unroll
      for (int nj = 0; nj < 4; nj++)
#pragma unroll
        for (int r = 0; r < 4; r++) {
          float p2 = __expf(sc * (sfr[nj][r] - m));   // masked -> exp(-inf) = 0
          sfr[nj][r] = p2;
          ps += p2;
        }
      ps += __shfl_xor(ps, 16, 64);
      ps += __shfl_xor(ps, 32, 64);
      lrow = lrow * fac + ps;
      float facr[4];
#pragma unroll
      for (int r = 0; r < 4; r++) facr[r] = __shfl(fac, g * 4 + r, 64);
#pragma unroll
      for (int nd = 0; nd < 4; nd++)
#pragma unroll
        for (int r = 0; r < 4; r++) acc[nd][r] *= facr[r];
      // P fragments: A-operand layout == swapped-MFMA C layout (same lane)
      FragU pa[2];
#pragma unroll
      for (int js = 0; js < 2; js++)
#pragma unroll
        for (int kk = 0; kk < 4; kk++) {
          pa[js].v[kk]     = (bf16_t)sfr[js * 2][kk];
          pa[js].v[kk + 4] = (bf16_t)sfr[js * 2 + 1][kk];
        }
#pragma unroll
      for (int js = 0; js < 2; js++)
#pragma unroll
        for (int nd = 0; nd < 4; nd++) {
          int d = nd * 16 + ln;
          FragU vb;
          vb.v = *reinterpret_cast<const bf16x8*>(&v_t[p][d * 64 + (((js * 4 + g) ^ (d & 7)) * 8)]);
          acc[nd] = __builtin_amdgcn_mfma_f32_16x16x32_bf16(pa[js].v, vb.v, acc[nd], 0, 0, 0);
        }
      barrier_raw();   // all waves done reading buffer p -> next iter may restage it
    }
    float lr[4];
#pragma unroll
    for (int r = 0; r < 4; r++) lr[r] = __shfl(lrow, g * 4 + r, 64);
    const int orow0 = i0 + w * 16 + g * 4;
#pragma unroll
    for (int nd = 0; nd < 4; nd++) {
      const int colp = permk(nd * 16 + ln);
#pragma unroll
      for (int r = 0; r < 4; r++) {
        int grow = orow0 + r;
        float o = (grow > 0 && lr[r] > 0.f) ? acc[nd][r] / lr[r] : 0.f;  // row0 zero_pad
        outp[base + (size_t)grow * DD + colp] = (bf16_t)o;
      }
    }
  }
}

extern "C" void kernel_launch(void* const* d_in, const int* in_sizes, int n_in,
                              void* d_out, int out_size, void* d_ws, size_t ws_size,
                              hipStream_t stream) {
  const float* q_emb  = (const float*)d_in[0];
  const float* qa_emb = (const float*)d_in[1];
  const float* bfp    = (const float*)d_in[2];
  const float* Wk  = (const float*)d_in[3];
  const float* bk  = (const float*)d_in[4];
  const float* Wv  = (const float*)d_in[5];
  const float* bv  = (const float*)d_in[6];
  const float* Wo  = (const float*)d_in[7];
  const float* bo  = (const float*)d_in[8];
  const float* g1  = (const float*)d_in[9];
  const float* be1 = (const float*)d_in[10];
  const float* W1  = (const float*)d_in[11];
  const float* b1  = (const float*)d_in[12];
  const float* W2  = (const float*)d_in[13];
  const float* b2  = (const float*)d_in[14];
  const float* g2  = (const float*)d_in[15];
  const float* be2 = (const float*)d_in[16];
  float* out = (float*)d_out;
  (void)in_sizes; (void)n_in; (void)out_size; (void)ws_size;

  char* wsp = (char*)d_ws;
  size_t off = 0;
  auto alloc = [&](size_t bytes) -> void* {
    void* p = wsp + off;
    off += (bytes + 255) & ~(size_t)255;
    return p;
  };
  const size_t BSD = (size_t)BB * SS * DD;
  float*  pe   = (float*) alloc((size_t)SS * DD * 4);
  bf16_t* xb   = (bf16_t*)alloc(BSD * 2);
  bf16_t* yb   = (bf16_t*)alloc(BSD * 2);
  bf16_t* qkb  = (bf16_t*)alloc(BSD * 2);
  bf16_t* vtg  = (bf16_t*)alloc((size_t)LL * BSD * 2);   // all 4 layers' V^T
  bf16_t* atb  = (bf16_t*)alloc(BSD * 2);
  bf16_t* tmpb = (bf16_t*)alloc(BSD * 2);
  bf16_t* h1   = (bf16_t*)alloc((size_t)BB * SS * FFD * 2);
  float*  g1p  = (float*) alloc((size_t)LL * DD * 4);
  float*  b1p  = (float*) alloc((size_t)LL * DD * 4);
  float*  g2p  = (float*) alloc((size_t)LL * DD * 4);
  float*  b2p  = (float*) alloc((size_t)LL * DD * 4);
  bf16_t* Wkb  = (bf16_t*)alloc((size_t)LL * DD * DD * 2);
  bf16_t* Wvb  = (bf16_t*)alloc((size_t)LL * DD * DD * 2);
  bf16_t* Wob  = (bf16_t*)alloc((size_t)LL * DD * DD * 2);
  bf16_t* W1b  = (bf16_t*)alloc((size_t)LL * DD * FFD * 2);
  bf16_t* W2b  = (bf16_t*)alloc((size_t)LL * FFD * DD * 2);

  pe_kernel<<<(SS * DD / 2 + 255) / 256, 256, 0, stream>>>(pe);
  gbperm_kernel<<<(LL * DD + 255) / 256, 256, 0, stream>>>(g1, be1, g2, be2, g1p, b1p, g2p, b2p);
  tcast_kernel<<<dim3(DD / 32, DD / 32, LL), 256, 0, stream>>>(Wk, Wkb, DD, DD);
  tcast_kernel<<<dim3(DD / 32, DD / 32, LL), 256, 0, stream>>>(Wv, Wvb, DD, DD);
  tcast_kernel<<<dim3(DD / 32, DD / 32, LL), 256, 0, stream>>>(Wo, Wob, DD, DD);
  tcast_kernel<<<dim3(FFD / 32, DD / 32, LL), 256, 0, stream>>>(W1, W1b, DD, FFD);
  tcast_kernel<<<dim3(DD / 32, FFD / 32, LL), 256, 0, stream>>>(W2, W2b, FFD, DD);
  addpe_kernel<<<(int)(BSD / 4 / 256), 256, 0, stream>>>(q_emb, qa_emb, pe, xb, yb);

  const int M = BB * SS;
  const int nD = (M / 128) * (DD / 128);          // 512 blocks
  const int nF = (M / 128) * (FFD / 128);         // 2048 blocks
  const int nV = (M / 128) * ((LL * DD) / 128);   // 2048 blocks (batched V, all layers)
  dim3 gA(SS / 128, HH, BB);       // paired q-tiles

  // batched V projection: v_l = y @ Wv[l] + bv[l] for all layers (y fixed)
  gemm_kernel<2, false><<<nV, 256, 0, stream>>>(yb, Wvb, bv, vtg, LL * DD, DD, (LL * DD) / 128);

  for (int layer = 0; layer < LL; layer++) {
    const bf16_t* Wkl = Wkb + (size_t)layer * DD * DD;
    const bf16_t* Wol = Wob + (size_t)layer * DD * DD;
    const bf16_t* W1l = W1b + (size_t)layer * DD * FFD;
    const bf16_t* W2l = W2b + (size_t)layer * FFD * DD;
    gemm_kernel<1, false><<<nD, 256, 0, stream>>>(xb, Wkl, bk + layer * DD, qkb, DD, DD, DD / 128);
    attn_kernel<<<gA, 256, 0, stream>>>(qkb, vtg + (size_t)layer * BSD, atb, bfp);
    gemm_kernel<1, false><<<nD, 256, 0, stream>>>(atb, Wol, bo + layer * DD, tmpb, DD, DD, DD / 128);
    lnp_kernel<false><<<M / 4, 256, 0, stream>>>(xb, tmpb, g1p + layer * DD, b1p + layer * DD, xb, nullptr);
    gemm_kernel<1, true><<<nF, 256, 0, stream>>>(xb, W1l, b1 + layer * FFD, h1, FFD, DD, FFD / 128);
    gemm_kernel<1, false><<<nD, 256, 0, stream>>>(h1, W2l, b2 + layer * DD, tmpb, DD, FFD, DD / 128);
    if (layer == LL - 1)
      lnp_kernel<true><<<M / 4, 256, 0, stream>>>(xb, tmpb, g2p + layer * DD, b2p + layer * DD, nullptr, out);
    else
      lnp_kernel<false><<<M / 4, 256, 0, stream>>>(xb, tmpb, g2p + layer * DD, b2p + layer * DD, xb, nullptr);
  }
}